// Round 14
// baseline (114.941 us; speedup 1.0000x reference)
//
#include <hip/hip_runtime.h>

typedef unsigned short u16;
typedef unsigned int u32;
typedef __bf16 bf16;
typedef __bf16 bf16x8 __attribute__((ext_vector_type(8)));
typedef __bf16 bf16x4 __attribute__((ext_vector_type(4)));
typedef float f32x4 __attribute__((ext_vector_type(4)));

#define NSAMP 2048
#define KH 3
#define NNBR 16
#define F 128
#define OUT_O 256   // C_OUT * F_OUT
#define QT 384      // KH * F

// LDS row stride MUST be a multiple of 8 elems (16 B) — misaligned b128 LDS
// ops get split by HW (R7). 136 elems = 272 B ok.
#define ZLD 136
#define YLD 136

__device__ __forceinline__ bf16x4 cvt4(float4 v) {
    bf16x4 h;
    h[0] = (bf16)v.x; h[1] = (bf16)v.y; h[2] = (bf16)v.z; h[3] = (bf16)v.w;
    return h;
}

__global__ void wprep(const float* __restrict__ W, bf16* __restrict__ Wbf) {
    int i = blockIdx.x * 256 + threadIdx.x;
    if (i < OUT_O * QT) Wbf[i] = (bf16)W[i];
}

// 1024-thread / 16-wave blocks. Each wave owns 16 output cols -> acc2 = 16
// AGPRs (vs 32 in the 512-thread design); GEMM1 = 2 tiles/wave (acc1 = 8);
// afrag built per-kk (4 transient). Adjacency build duplicated across the two
// wave-halves (same per-thread cost). Target: <=64 total regs -> 32 waves/CU.
__launch_bounds__(1024, 8)
__global__ void featkhop(const float* __restrict__ xg,
                         const float* __restrict__ ng,
                         const bf16* __restrict__ Wbf,
                         float* __restrict__ out) {
    // Zs rows 0..48 = x + 48 neighbors (bf16); rows 49..63 are read by MFMA
    // as don't-care garbage (output rows discarded); f32 scratch aliases that
    // tail (2560 B of 4080 B), all barrier-ordered.
    __shared__ __align__(16) bf16 Zs[64 * ZLD];       // 17408 B
    __shared__ __align__(16) bf16 Ys[64 * YLD];       // 17408 B (single buffer)
    float* const xls = (float*)(Zs + 49 * ZLD);       // 128 f32 (byte 13328, 16B-aligned)
    float* const sls = xls + F;                        // [3][128] f32
    float* const rsi = xls + 4 * F;                    // 128 f32, per current q

    const int i = blockIdx.x;
    const int t = threadIdx.x;
    const int lane = t & 63;
    const int w = t >> 6;        // wave 0..15
    const int wh = w & 7;        // a-tile owner
    const int half = w >> 3;     // v-half for GEMM1
    const int lr = lane & 15;
    const int lg = lane >> 4;

    // ---- stage x ----
    if (t < F / 4) {
        float4 v = *(const float4*)(xg + (size_t)i * F + t * 4);
        *(float4*)(xls + t * 4) = v;
        *(bf16x4*)(Zs + 0 * ZLD + t * 4) = cvt4(v);
    }
    // ---- stage neighbors: 1536 float4 over 1024 threads ----
    const float* nb = ng + (size_t)i * (KH * NNBR * F);
    {
        {
            int j = t;
            float4 v = *(const float4*)(nb + j * 4);
            int fl = j * 4;
            *(bf16x4*)(Zs + (1 + (fl >> 7)) * ZLD + (fl & 127)) = cvt4(v);
        }
        if (t < 512) {
            int j = 1024 + t;
            float4 v = *(const float4*)(nb + j * 4);
            int fl = j * 4;
            *(bf16x4*)(Zs + (1 + (fl >> 7)) * ZLD + (fl & 127)) = cvt4(v);
        }
    }
    // ---- s[q][b] from GLOBAL f32 (L2-hot) ----
    if (t < KH * F) {
        int q = t >> 7, b = t & 127;
        float s = 0.f;
        #pragma unroll
        for (int n = 0; n < NNBR; ++n) s += nb[(q * NNBR + n) * F + b];
        sls[q * F + b] = s;
    }
    __syncthreads();                     // bar S

    const int a_row = wh * 16 + lr;      // adjacency row this lane owns
    const float x_a = xls[a_row];
    const int cbase = lg * 8;

    f32x4 acc2[4];
    {
        f32x4 zf = {0.f, 0.f, 0.f, 0.f};
        #pragma unroll
        for (int mt = 0; mt < 4; ++mt) acc2[mt] = zf;
    }

    for (int q = 0; q < KH; ++q) {
        // ---- build u-row (bf16, 16 regs); rowsum (=colsum by symmetry) ----
        const float s_a = sls[q * F + a_row];
        bf16x8 uvh[4];
        float ps = 0.f;
        #pragma unroll
        for (int kk = 0; kk < 4; ++kk) {
            float4 xb0 = *(const float4*)(xls + kk * 32 + cbase);
            float4 xb1 = *(const float4*)(xls + kk * 32 + cbase + 4);
            float4 sb0 = *(const float4*)(sls + q * F + kk * 32 + cbase);
            float4 sb1 = *(const float4*)(sls + q * F + kk * 32 + cbase + 4);
            float xb[8] = {xb0.x, xb0.y, xb0.z, xb0.w, xb1.x, xb1.y, xb1.z, xb1.w};
            float sb[8] = {sb0.x, sb0.y, sb0.z, sb0.w, sb1.x, sb1.y, sb1.z, sb1.w};
            #pragma unroll
            for (int e = 0; e < 8; ++e) {
                float tv = x_a * sb[e] + xb[e] * s_a;
                float r = tv * __builtin_amdgcn_rsqf(fmaxf(fabsf(tv), 1e-8f));
                uvh[kk][e] = (bf16)r;
                ps += fabsf(r);
            }
        }
        ps += __shfl_xor(ps, 16);
        ps += __shfl_xor(ps, 32);
        if (lg == 0 && half == 0) rsi[a_row] = __builtin_amdgcn_rcpf(ps + 1e-7f);
        __syncthreads();                 // bar A(q): rsi ready; Ys free (prev GEMM2 done)

        // ---- GEMM1 (swapped): Y^T = adj * Z^T; afrag per-kk (4 transient regs)
        //      wave (wh, half): a-tile wh, v-tiles {half*2, half*2+1} ----
        f32x4 a10 = {0.f, 0.f, 0.f, 0.f};
        f32x4 a11 = {0.f, 0.f, 0.f, 0.f};
        #pragma unroll
        for (int kk = 0; kk < 4; ++kk) {
            float4 r0 = *(const float4*)(rsi + kk * 32 + cbase);
            float4 r1 = *(const float4*)(rsi + kk * 32 + cbase + 4);
            float rb[8] = {r0.x, r0.y, r0.z, r0.w, r1.x, r1.y, r1.z, r1.w};
            bf16x8 afrag;
            #pragma unroll
            for (int e = 0; e < 8; ++e)
                afrag[e] = (bf16)((float)uvh[kk][e] * rb[e]);
            bf16x8 zf0 = *(const bf16x8*)(Zs + (half * 32 + lr) * ZLD + kk * 32 + cbase);
            bf16x8 zf1 = *(const bf16x8*)(Zs + (half * 32 + 16 + lr) * ZLD + kk * 32 + cbase);
            a10 = __builtin_amdgcn_mfma_f32_16x16x32_bf16(afrag, zf0, a10, 0, 0, 0);
            a11 = __builtin_amdgcn_mfma_f32_16x16x32_bf16(afrag, zf1, a11, 0, 0, 0);
        }
        // D: lane holds Y^T[a = wh*16 + lg*4+r][v = vt*16+lr] -> b64 store to Ys[v][a]
        {
            bf16x4 yv0, yv1;
            #pragma unroll
            for (int r = 0; r < 4; ++r) { yv0[r] = (bf16)a10[r]; yv1[r] = (bf16)a11[r]; }
            *(bf16x4*)(Ys + (half * 32 + lr) * YLD + wh * 16 + lg * 4) = yv0;
            *(bf16x4*)(Ys + (half * 32 + 16 + lr) * YLD + wh * 16 + lg * 4) = yv1;
        }
        __syncthreads();                 // bar B(q): Ys complete

        // ---- GEMM2 (q-slice): acc2 += Y_q(64x128) @ Wq^T; wave owns o = w*16+lr ----
        #pragma unroll
        for (int kk = 0; kk < 4; ++kk) {
            bf16x8 wf = *(const bf16x8*)(Wbf + (size_t)(w * 16 + lr) * QT + q * F + kk * 32 + cbase);
            #pragma unroll
            for (int mt = 0; mt < 4; ++mt) {
                bf16x8 af = *(const bf16x8*)(Ys + (mt * 16 + lr) * YLD + kk * 32 + cbase);
                acc2[mt] = __builtin_amdgcn_mfma_f32_16x16x32_bf16(af, wf, acc2[mt], 0, 0, 0);
            }
        }
        // loop-back: build(q+1) touches only regs + rsi (whose q-readers all
        // finished before bar B(q)); GEMM1(q+1)'s Ys writes are after bar A(q+1),
        // which every wave reaches only after finishing this GEMM2.
    }

    // ---- epilogue: v=0 -> x_out, v=1..48 -> nbr_out; o = w*16+lr ----
    float* xout = out + (size_t)i * OUT_O;
    float* nout = out + (size_t)NSAMP * OUT_O + (size_t)i * 48 * OUT_O;
    const int o = w * 16 + lr;
    #pragma unroll
    for (int mt = 0; mt < 4; ++mt) {
        #pragma unroll
        for (int r = 0; r < 4; ++r) {
            int v = mt * 16 + lg * 4 + r;
            float val = acc2[mt][r];
            if (v == 0) xout[o] = val;
            else if (v <= 48) nout[(size_t)(v - 1) * OUT_O + o] = val;
        }
    }
}

extern "C" void kernel_launch(void* const* d_in, const int* in_sizes, int n_in,
                              void* d_out, int out_size, void* d_ws, size_t ws_size,
                              hipStream_t stream) {
    const float* x   = (const float*)d_in[0];
    const float* nbr = (const float*)d_in[1];
    const float* W   = (const float*)d_in[2];
    bf16* Wbf = (bf16*)d_ws;   // 256*384 bf16 = 192 KiB
    wprep<<<(OUT_O * QT + 255) / 256, 256, 0, stream>>>(W, Wbf);
    featkhop<<<NSAMP, 1024, 0, stream>>>(x, nbr, Wbf, (float*)d_out);
}